// Round 15
// baseline (909.249 us; speedup 1.0000x reference)
//
#include <hip/hip_runtime.h>
#include <hip/hip_bf16.h>
#include <stdint.h>

typedef unsigned short ushort_t;
typedef unsigned int uint_t;

typedef __bf16 bf16x8 __attribute__((ext_vector_type(8)));
typedef float f32x4 __attribute__((ext_vector_type(4)));
typedef short short4v __attribute__((ext_vector_type(4)));
typedef short short8v __attribute__((ext_vector_type(8)));

typedef const __attribute__((address_space(1))) void gv_t;
typedef __attribute__((address_space(3))) void lv_t;

__device__ __forceinline__ ushort_t f2b(float f) {
  uint_t u = __builtin_bit_cast(uint_t, f);
  u += 0x7FFFu + ((u >> 16) & 1u);   // round-to-nearest-even
  return (ushort_t)(u >> 16);
}
__device__ __forceinline__ float b2f(ushort_t s) {
  return __builtin_bit_cast(float, (uint_t)s << 16);
}
constexpr int ilog2c(int x) { return x <= 1 ? 0 : 1 + ilog2c(x >> 1); }

constexpr int Tt = 16, Cc = 256, Hh = 64, Ww = 64, DKc = 128;
constexpr size_t P1OFFc = 16777216;   // patch-1 offset within token regions (elems)

// ---------------- tokenize Q and K, LDS-free register transpose (R11-verified) ----------------
__global__ __launch_bounds__(256) void tok_qk3(const float* __restrict__ srcQ, const float* __restrict__ srcK,
                                               ushort_t* __restrict__ dstQ, ushort_t* __restrict__ dstK) {
  const int blk = blockIdx.x;
  const int sel = blk >> 11;
  const int bt  = (blk >> 6) & 31;
  const int cg  = blk & 63;
  const int b = bt >> 4, t = bt & 15;
  const float* src = sel ? srcK : srcQ;
  ushort_t* dst = sel ? dstK : dstQ;
  const int tid = threadIdx.x;
  const int w = tid >> 6, l = tid & 63;
  if (cg < 32) {
    const int c = cg * 4 + w;
    const float* img = src + (((size_t)(bt * 256 + c)) << 12);
    const int oh = l >> 3, ow = l & 7;
    ushort_t* out = dst + (((size_t)(b * 1024 + t * 64 + l)) << 13) + c * 64;
    const float* base = img + (oh * 8) * 64 + ow * 8;
#pragma unroll
    for (int py = 0; py < 8; ++py) {
      float4 f0 = *(const float4*)(base + py * 64);
      float4 f1 = *(const float4*)(base + py * 64 + 4);
      short8v o;
      o[0] = (short)f2b(f0.x); o[1] = (short)f2b(f0.y); o[2] = (short)f2b(f0.z); o[3] = (short)f2b(f0.w);
      o[4] = (short)f2b(f1.x); o[5] = (short)f2b(f1.y); o[6] = (short)f2b(f1.z); o[7] = (short)f2b(f1.w);
      *(short8v*)(out + py * 8) = o;
    }
  } else {
    const int c = 128 + (cg - 32) * 4 + w;
    const float* img = src + (((size_t)(bt * 256 + c)) << 12);
    const int ow = l & 15, ohg = l >> 4;
#pragma unroll
    for (int i = 0; i < 4; ++i) {
      const int oh = ohg + 4 * i;
      const int n = t * 256 + oh * 16 + ow;
      ushort_t* out = dst + P1OFFc + (((size_t)(b * 4096 + n)) << 11) + (c - 128) * 16;
      const float* basep = img + (oh * 4) * 64 + ow * 4;
      float4 f0 = *(const float4*)(basep);
      float4 f1 = *(const float4*)(basep + 64);
      float4 f2 = *(const float4*)(basep + 128);
      float4 f3 = *(const float4*)(basep + 192);
      short8v o0, o1;
      o0[0] = (short)f2b(f0.x); o0[1] = (short)f2b(f0.y); o0[2] = (short)f2b(f0.z); o0[3] = (short)f2b(f0.w);
      o0[4] = (short)f2b(f1.x); o0[5] = (short)f2b(f1.y); o0[6] = (short)f2b(f1.z); o0[7] = (short)f2b(f1.w);
      o1[0] = (short)f2b(f2.x); o1[1] = (short)f2b(f2.y); o1[2] = (short)f2b(f2.z); o1[3] = (short)f2b(f2.w);
      o1[4] = (short)f2b(f3.x); o1[5] = (short)f2b(f3.y); o1[6] = (short)f2b(f3.z); o1[7] = (short)f2b(f3.w);
      *(short8v*)out = o0;
      *(short8v*)(out + 8) = o1;
    }
  }
}

// ---------------- tokenize V transposed via LDS tile, [64][65] pad (R12-verified) ----------------
__global__ __launch_bounds__(256) void tok_v4(const float* __restrict__ src, ushort_t* __restrict__ dst) {
  __shared__ float lds[64][65];
  const int blk = blockIdx.x;
  const int c  = blk & 255;
  const int bt = blk >> 8;
  const int b  = bt >> 4, t = bt & 15;
  const int tid = threadIdx.x;
  const float* img = src + ((size_t)blk << 12);
  {
    const int h = tid >> 2, w0 = (tid & 3) << 4;
    const float* s = img + h * 64 + w0;
    float4 f0 = *(const float4*)(s);
    float4 f1 = *(const float4*)(s + 4);
    float4 f2 = *(const float4*)(s + 8);
    float4 f3 = *(const float4*)(s + 12);
    float* d = &lds[h][w0];
    d[0] = f0.x; d[1] = f0.y; d[2]  = f0.z; d[3]  = f0.w;
    d[4] = f1.x; d[5] = f1.y; d[6]  = f1.z; d[7]  = f1.w;
    d[8] = f2.x; d[9] = f2.y; d[10] = f2.z; d[11] = f2.w;
    d[12] = f3.x; d[13] = f3.y; d[14] = f3.z; d[15] = f3.w;
  }
  __syncthreads();
  if (c < 128) {
    const int dd = tid >> 2, cc = tid & 3;
    const int py = dd >> 3, px = dd & 7;
    ushort_t* out = dst + (((size_t)(b * 8192 + c * 64 + dd)) << 10) + t * 64 + cc * 16;
    short8v o0, o1;
#pragma unroll
    for (int j = 0; j < 8; ++j) {
      const int n = cc * 16 + j;
      o0[j] = (short)f2b(lds[(n >> 3) * 8 + py][(n & 7) * 8 + px]);
    }
#pragma unroll
    for (int j = 8; j < 16; ++j) {
      const int n = cc * 16 + j;
      o1[j - 8] = (short)f2b(lds[(n >> 3) * 8 + py][(n & 7) * 8 + px]);
    }
    *(short8v*)out = o0;
    *(short8v*)(out + 8) = o1;
  } else {
    const int dd = tid >> 4, cc = tid & 15;
    const int py = dd >> 2, px = dd & 3;
    ushort_t* out = dst + P1OFFc + (((size_t)(b * 2048 + (c - 128) * 16 + dd)) << 12) + t * 256 + cc * 16;
    short8v o0, o1;
#pragma unroll
    for (int j = 0; j < 8; ++j)
      o0[j] = (short)f2b(lds[cc * 4 + py][j * 4 + px]);
#pragma unroll
    for (int j = 8; j < 16; ++j)
      o1[j - 8] = (short)f2b(lds[cc * 4 + py][j * 4 + px]);
    *(short8v*)out = o0;
    *(short8v*)(out + 8) = o1;
  }
}

__device__ __forceinline__ void waitvm6()  { asm volatile("s_waitcnt vmcnt(6)"  ::: "memory"); }
__device__ __forceinline__ void waitvm8()  { asm volatile("s_waitcnt vmcnt(8)"  ::: "memory"); }
__device__ __forceinline__ void waitvm0()  { asm volatile("s_waitcnt vmcnt(0)"  ::: "memory"); }

// ---- 256x256/BK=64 double-buffered NT GEMM, 4 quadrant-phases/K-tile ----
// ADIR=false: R13-verified path (A+B via LDS, 2 barriers/tile, counted vmcnt(6)).
// ADIR=true (sound v2): A-fragments are PLAIN global loads (read-only -> any compiler
//   reorder is harmless; compiler inserts its own counted waits). B staged to LDS at P3,
//   strictly AFTER the P2-end barrier (all B readers consumed their ds_reads before that
//   barrier -> cross-wave WAR sound). Landing guarantee: single vmcnt(0) after P2's MFMA
//   (outstanding there ~0: Am1 needed anyway; next stgB not yet issued) -> count-
//   independent of plain-load scheduling. LDS = 64 KiB (B double-buffer only).
template<int EPI, int KSPLIT, int LDK, int NP, int PH, int PW, int CBASE, bool ADIR>
__global__ __launch_bounds__(512, 2)
void gemm_pipe(const ushort_t* __restrict__ A, const ushort_t* __restrict__ B,
               size_t aBatch, size_t bBatch, int nt,
               void* __restrict__ outPtr, size_t oBatch, float scale) {
  constexpr int LDSE = ADIR ? (2 * 256 * 64) : (4 * 256 * 64);
  __shared__ __align__(16) ushort_t LDSU[LDSE];
  ushort_t* Bs = LDSU;
  ushort_t* As = ADIR ? LDSU : (LDSU + 2 * 256 * 64);

  const int tid = threadIdx.x;
  const int w = tid >> 6, l = tid & 63;
  const int wm = w >> 2, wn = w & 3;
  const int lr = l & 15, lk = l >> 4;
  const int srow8 = tid >> 3;
  const int gcolS = (((tid & 7) ^ (srow8 & 7)) << 3);
  const int sw0 = ((lk ^ (lr & 7)) << 4);
  const int sw1 = sw0 ^ 64;

  const int gx = gridDim.x, gy = gridDim.y, gz = gridDim.z;
  int id = (blockIdx.z * gy + blockIdx.y) * gx + blockIdx.x;
  const int cpx = (gx * gy * gz) >> 3;
  id = (id & 7) * cpx + (id >> 3);
  const int bx = id % gx;
  const int rst = id / gx;
  const int by = rst % gy;
  const int bz = rst / gy;

  int batch = bz, ks = 0;
  if constexpr (KSPLIT > 1) { batch = bz / KSPLIT; ks = bz - batch * KSPLIT; }

  const int rowBase = by * 256, colBase = bx * 256;
  const ushort_t* Ab = A + (size_t)batch * aBatch + (size_t)ks * nt * 64;
  const ushort_t* Bb = B + (size_t)batch * bBatch + (size_t)ks * nt * 64;

  const ushort_t* pB[4];
#pragma unroll
  for (int r = 0; r < 4; ++r)
    pB[r] = Bb + (size_t)(colBase + r * 64 + srow8) * LDK + gcolS;

  const ushort_t* pA[4];
  const ushort_t* aB[4];
  if constexpr (!ADIR) {
#pragma unroll
    for (int r = 0; r < 4; ++r)
      pA[r] = Ab + (size_t)(rowBase + r * 64 + srow8) * LDK + gcolS;
  } else {
#pragma unroll
    for (int mi = 0; mi < 4; ++mi)
      aB[mi] = Ab + (size_t)(rowBase + wm * 128 + mi * 16 + lr) * LDK + lk * 8;
  }
  constexpr size_t MH1 = (size_t)64 * LDK;

  const char* ArdBase0 = (const char*)As + (wm * 128 + lr) * 128 + sw0;
  const char* ArdBase1 = (const char*)As + (wm * 128 + lr) * 128 + sw1;
  const char* BrdBase0 = (const char*)Bs + (wn * 64 + lr) * 128 + sw0;
  const char* BrdBase1 = (const char*)Bs + (wn * 64 + lr) * 128 + sw1;

  f32x4 acc[8][4] = {};
  bf16x8 Am0[8], Am1[8], Bn0[4], Bn1[4];

  auto stgA = [&](int bufB, int r, int elemOff) {
    __builtin_amdgcn_global_load_lds((gv_t*)(pA[r] + elemOff),
        (lv_t*)((char*)As + bufB + r * 8192 + w * 1024), 16, 0, 0);
  };
  auto stgB = [&](int bufB, int r, int elemOff) {
    __builtin_amdgcn_global_load_lds((gv_t*)(pB[r] + elemOff),
        (lv_t*)((char*)Bs + bufB + r * 8192 + w * 1024), 16, 0, 0);
  };
  auto rdA = [&](int off, bf16x8* dst) {
#pragma unroll
    for (int mi = 0; mi < 4; ++mi) {
      dst[mi * 2 + 0] = *(const bf16x8*)(ArdBase0 + off + mi * 2048);
      dst[mi * 2 + 1] = *(const bf16x8*)(ArdBase1 + off + mi * 2048);
    }
  };
  auto rdAg = [&](int mh, int eoff, bf16x8* dst) {   // plain global A fragments
#pragma unroll
    for (int mi = 0; mi < 4; ++mi) {
      const ushort_t* p = aB[mi] + (mh ? MH1 : 0) + eoff;
      dst[mi * 2 + 0] = *(const bf16x8*)(p);
      dst[mi * 2 + 1] = *(const bf16x8*)(p + 32);
    }
  };
  auto rdB = [&](int off, bf16x8* dst) {
#pragma unroll
    for (int ni = 0; ni < 2; ++ni) {
      dst[ni * 2 + 0] = *(const bf16x8*)(BrdBase0 + off + ni * 2048);
      dst[ni * 2 + 1] = *(const bf16x8*)(BrdBase1 + off + ni * 2048);
    }
  };
  auto mmq = [&](const bf16x8* a, const bf16x8* b, int mh, int nh) {
    __builtin_amdgcn_s_setprio(1);
#pragma unroll
    for (int mi = 0; mi < 4; ++mi)
#pragma unroll
      for (int ni = 0; ni < 2; ++ni) {
        f32x4& cc = acc[mh * 4 + mi][nh * 2 + ni];
        cc = __builtin_amdgcn_mfma_f32_16x16x32_bf16(a[mi * 2 + 0], b[ni * 2 + 0], cc, 0, 0, 0);
        cc = __builtin_amdgcn_mfma_f32_16x16x32_bf16(a[mi * 2 + 1], b[ni * 2 + 1], cc, 0, 0, 0);
      }
    __builtin_amdgcn_s_setprio(0);
  };

  // ---- prologue ----
  if constexpr (ADIR) {
#pragma unroll
    for (int r = 0; r < 4; ++r) stgB(0, r, 0);
#pragma unroll
    for (int r = 0; r < 4; ++r) stgB(32768, r, 64);
    rdAg(0, 0, Am0);                 // tile-0 mh0 (plain loads; compiler-waited at use)
#pragma unroll
    for (int r = 0; r < 4; ++r) pB[r] += 128;   // pB at kt=2; aB stays at pair base kt=0
    waitvm0();                        // sound under any load reordering
    __builtin_amdgcn_s_barrier();
    rdB(0, Bn0);
  } else {
#pragma unroll
    for (int r = 0; r < 4; ++r) stgA(0, r, 0);
#pragma unroll
    for (int r = 0; r < 4; ++r) stgB(0, r, 0);
#pragma unroll
    for (int r = 0; r < 4; ++r) stgA(32768, r, 64);
#pragma unroll
    for (int r = 0; r < 4; ++r) stgB(32768, r, 64);
#pragma unroll
    for (int r = 0; r < 4; ++r) { pA[r] += 128; pB[r] += 128; }
    waitvm8();
    __builtin_amdgcn_s_barrier();
    rdA(0, Am0);
    rdB(0, Bn0);
  }

  auto tb = [&](int T, int BUFB, int EOFF, int ADV) {
    const int OB = BUFB ^ 32768;
    if constexpr (ADIR) {
      // P0: read-ahead Bn1 (ds); MFMA q(0,0)
      rdB(BUFB + 4096, Bn1);
      mmq(Am0, Bn0, 0, 0);
      __builtin_amdgcn_s_barrier();
      // P1: A mh1 plain-global; MFMA q(0,1)  (Bn1 consumed here, before P2-end barrier)
      rdAg(1, EOFF, Am1);
      mmq(Am0, Bn1, 0, 1);
      // P2: MFMA q(1,0); full drain (cheap: ~0 outstanding) -> stgB(t+1) landed; barrier
      mmq(Am1, Bn0, 1, 0);
      waitvm0();
      __builtin_amdgcn_s_barrier();
      // P3: next-tile A mh0 + Bn0 read-ahead; stage B(t+2) into CURRENT buffer (WAR-safe:
      // all readers of this buffer completed before the P2-end barrier); MFMA q(1,1)
      if (T + 1 < nt) { rdAg(0, EOFF + 64, Am0); rdB(OB, Bn0); }
      if (T + 2 < nt) { stgB(BUFB, 0, EOFF); stgB(BUFB, 1, EOFF);
                        stgB(BUFB, 2, EOFF); stgB(BUFB, 3, EOFF); }
      if (ADV) {
#pragma unroll
        for (int r = 0; r < 4; ++r) pB[r] += 128;
#pragma unroll
        for (int mi = 0; mi < 4; ++mi) aB[mi] += 128;
      }
      mmq(Am1, Bn1, 1, 1);
    } else {
      // P0: MFMA q(0,0); read-ahead B-half1
      rdB(BUFB + 4096, Bn1);
      mmq(Am0, Bn0, 0, 0);
      __builtin_amdgcn_s_barrier();
      // P1: read-ahead A-half1; stage t+2 A rounds 0,2; MFMA q(0,1)
      rdA(BUFB + 8192, Am1);
      if (T + 2 < nt) { stgA(BUFB, 0, EOFF); stgA(BUFB, 2, EOFF); }
      mmq(Am0, Bn1, 0, 1);
      // P2: MFMA q(1,0); stage t+2 B all; counted drain before kept barrier
      if (T + 2 < nt) { stgB(BUFB, 0, EOFF); stgB(BUFB, 1, EOFF);
                        stgB(BUFB, 2, EOFF); stgB(BUFB, 3, EOFF); }
      mmq(Am1, Bn0, 1, 0);
      if (T + 2 < nt) waitvm6(); else if (T + 1 < nt) waitvm0();
      __builtin_amdgcn_s_barrier();
      // P3: read-ahead next tile A0,B0; stage t+2 A rounds 1,3; MFMA q(1,1)
      if (T + 1 < nt) { rdA(OB, Am0); rdB(OB, Bn0); }
      if (T + 2 < nt) {
        stgA(BUFB, 1, EOFF); stgA(BUFB, 3, EOFF);
        if (ADV) {
#pragma unroll
          for (int r = 0; r < 4; ++r) { pA[r] += 128; pB[r] += 128; }
        }
      }
      mmq(Am1, Bn1, 1, 1);
    }
  };

  for (int t = 0; t < nt; t += 2) {
    tb(t, 0, 0, 0);
    tb(t + 1, 32768, 64, 1);
  }

  if constexpr (EPI == 0) {
    ushort_t* P = (ushort_t*)outPtr + (size_t)batch * oBatch;
#pragma unroll
    for (int mi = 0; mi < 8; ++mi) {
      const int row0 = rowBase + wm * 128 + mi * 16 + lk * 4;
#pragma unroll
      for (int ni = 0; ni < 4; ++ni) {
        const int col = colBase + wn * 64 + ni * 16 + lr;
#pragma unroll
        for (int r = 0; r < 4; ++r)
          P[(size_t)(row0 + r) * NP + col] = f2b(acc[mi][ni][r] * scale);
      }
    }
  } else if constexpr (EPI == 1) {
    float* O = (float*)outPtr;
    constexpr int OWN = Ww / PW;
    constexpr int OHW = (Hh / PH) * OWN;
    constexpr int PHPW = PH * PW;
#pragma unroll
    for (int mi = 0; mi < 8; ++mi) {
#pragma unroll
      for (int ni = 0; ni < 4; ++ni) {
        const int d = colBase + wn * 64 + ni * 16 + lr;
        const int c   = d >> ilog2c(PHPW);
        const int pyx = d & (PHPW - 1);
        const int py  = pyx >> ilog2c(PW);
        const int px  = pyx & (PW - 1);
#pragma unroll
        for (int r = 0; r < 4; ++r) {
          const int qq = rowBase + wm * 128 + mi * 16 + lk * 4 + r;
          const int tt = qq >> ilog2c(OHW);
          const int rm = qq & (OHW - 1);
          const int oh = rm >> ilog2c(OWN);
          const int ow = rm & (OWN - 1);
          size_t off = (((size_t)((batch * Tt + tt) * Cc + CBASE + c)) << 12)
                     + ((oh * PH + py) << 6) + ow * PW + px;
          O[off] = acc[mi][ni][r];
        }
      }
    }
  } else {
    const int nb = gz / KSPLIT;
    ushort_t* O = (ushort_t*)outPtr + ((size_t)ks * nb + batch) * oBatch;
#pragma unroll
    for (int mi = 0; mi < 8; ++mi) {
      const int row0 = rowBase + wm * 128 + mi * 16 + lk * 4;
#pragma unroll
      for (int ni = 0; ni < 4; ++ni) {
        const int col = colBase + wn * 64 + ni * 16 + lr;
#pragma unroll
        for (int r = 0; r < 4; ++r)
          O[(size_t)(row0 + r) * NP + col] = f2b(acc[mi][ni][r] * scale);
      }
    }
  }
}

// ---------------- row softmax over bf16 scores, in place ----------------
template<int NP>
__global__ __launch_bounds__(256) void softmax_rows(ushort_t* __restrict__ P) {
  constexpr int PER = NP / 256;
  constexpr int CH  = NP / 1024;
  ushort_t* row = P + (size_t)blockIdx.x * NP;
  const int tid = threadIdx.x;
  float v[PER];
  #pragma unroll
  for (int j = 0; j < CH; ++j) {
    short4v s = *(const short4v*)(row + j * 1024 + tid * 4);
    #pragma unroll
    for (int jj = 0; jj < 4; ++jj) v[4 * j + jj] = b2f((ushort_t)s[jj]);
  }
  float m = -1e30f;
  #pragma unroll
  for (int j = 0; j < PER; ++j) m = fmaxf(m, v[j]);
  #pragma unroll
  for (int o = 32; o >= 1; o >>= 1) m = fmaxf(m, __shfl_xor(m, o));
  __shared__ float redm[4];
  if ((tid & 63) == 0) redm[tid >> 6] = m;
  __syncthreads();
  m = fmaxf(fmaxf(redm[0], redm[1]), fmaxf(redm[2], redm[3]));
  float sum = 0.f;
  #pragma unroll
  for (int j = 0; j < PER; ++j) { v[j] = __expf(v[j] - m); sum += v[j]; }
  #pragma unroll
  for (int o = 32; o >= 1; o >>= 1) sum += __shfl_xor(sum, o);
  __shared__ float reds[4];
  if ((tid & 63) == 0) reds[tid >> 6] = sum;
  __syncthreads();
  sum = reds[0] + reds[1] + reds[2] + reds[3];
  const float inv = 1.0f / sum;
  #pragma unroll
  for (int j = 0; j < CH; ++j) {
    short4v o;
    #pragma unroll
    for (int jj = 0; jj < 4; ++jj) o[jj] = (short)f2b(v[4 * j + jj] * inv);
    *(short4v*)(row + j * 1024 + tid * 4) = o;
  }
}

// ---------------- combine 8 bf16 split-K partials + softmax -> bf16 P (patch 0) ----------------
__global__ __launch_bounds__(256) void softmax_combine_p0(const ushort_t* __restrict__ part,
                                                          ushort_t* __restrict__ P) {
  const int tid = threadIdx.x;
  const int b = blockIdx.x >> 10;
  const int m = blockIdx.x & 1023;
  float v[4] = {0.f, 0.f, 0.f, 0.f};
  #pragma unroll
  for (int ks = 0; ks < 8; ++ks) {
    short4v a = *(const short4v*)(part + ((size_t)(ks * 2 + b) * 1024 + m) * 1024 + tid * 4);
    #pragma unroll
    for (int j = 0; j < 4; ++j) v[j] += b2f((ushort_t)a[j]);
  }
  float mx = fmaxf(fmaxf(v[0], v[1]), fmaxf(v[2], v[3]));
  #pragma unroll
  for (int o = 32; o >= 1; o >>= 1) mx = fmaxf(mx, __shfl_xor(mx, o));
  __shared__ float redm[4], reds[4];
  if ((tid & 63) == 0) redm[tid >> 6] = mx;
  __syncthreads();
  mx = fmaxf(fmaxf(redm[0], redm[1]), fmaxf(redm[2], redm[3]));
  float sum = 0.f;
  #pragma unroll
  for (int j = 0; j < 4; ++j) { v[j] = __expf(v[j] - mx); sum += v[j]; }
  #pragma unroll
  for (int o = 32; o >= 1; o >>= 1) sum += __shfl_xor(sum, o);
  if ((tid & 63) == 0) reds[tid >> 6] = sum;
  __syncthreads();
  sum = reds[0] + reds[1] + reds[2] + reds[3];
  const float inv = 1.0f / sum;
  short4v o4;
  #pragma unroll
  for (int j = 0; j < 4; ++j) o4[j] = (short)f2b(v[j] * inv);
  *(short4v*)(P + ((size_t)(b * 1024 + m)) * 1024 + tid * 4) = o4;
}

extern "C" void kernel_launch(void* const* d_in, const int* in_sizes, int n_in,
                              void* d_out, int out_size, void* d_ws, size_t ws_size,
                              hipStream_t stream) {
  const float* q = (const float*)d_in[0];
  const float* k = (const float*)d_in[1];
  const float* v = (const float*)d_in[2];
  ushort_t* wsA = (ushort_t*)d_ws;
  ushort_t* wsB = wsA + (size_t)33554432;          // 64 MiB in
  ushort_t* wsP = wsB + (size_t)33554432;          // 128 MiB in
  const size_t P1OFF = P1OFFc;                     // patch-1 offset within A/B regions (elems)
  const size_t PP1   = 2097152;                    // patch-1 offset within P region (elems)
  ushort_t* part = wsP + PP1;                      // QK-p0 bf16 split-K partials (32 MiB), overlaid on P-p1

  // tokenize Q and K (merged, both patches, LDS-free register transpose)
  tok_qk3<<<4096, 256, 0, stream>>>(q, k, wsA, wsB);

  // QK p0: split-K=8 -> bf16 partials; fused combine+softmax (A-panel too big for L2 -> LDS path)
  gemm_pipe<2, 8, 8192, 1024, 1, 1, 0, false><<<dim3(4, 4, 16), 512, 0, stream>>>(
      wsA, wsB, (size_t)1024 * 8192, (size_t)1024 * 8192, 16,
      part, (size_t)1048576, 0.011048543456039806f);
  softmax_combine_p0<<<2048, 256, 0, stream>>>(part, wsP);

  // QK p1: ADIR (A-panels 1 MB, col-blocks of one panel co-resident per XCD -> L2-served)
  gemm_pipe<0, 1, 2048, 4096, 1, 1, 0, true><<<dim3(16, 16, 2), 512, 0, stream>>>(
      wsA + P1OFF, wsB + P1OFF, (size_t)4096 * 2048, (size_t)4096 * 2048, 32,
      wsP + PP1, (size_t)4096 * 4096, 0.022097086912079612f);
  softmax_rows<4096><<<8192, 256, 0, stream>>>(wsP + PP1);

  // tokenize V transposed into A region (Q tokens no longer needed)
  tok_v4<<<8192, 256, 0, stream>>>(v, wsA);

  // O = P * V -> scatter fp32 into d_out
  // PV p0: ADIR (A-panels 0.5 MB, L2-resident)
  gemm_pipe<1, 1, 1024, 0, 8, 8, 0, true><<<dim3(32, 4, 2), 512, 0, stream>>>(
      wsP, wsA, (size_t)1024 * 1024, (size_t)8192 * 1024, 16, d_out, 0, 1.0f);
  // PV p1: A-panels 2 MB x several concurrent -> keep LDS path
  gemm_pipe<1, 1, 4096, 0, 4, 4, 128, false><<<dim3(8, 16, 2), 512, 0, stream>>>(
      wsP + PP1, wsA + P1OFF, (size_t)4096 * 4096, (size_t)2048 * 4096, 64, d_out, 0, 1.0f);
}

// Round 16
// 484.107 us; speedup vs baseline: 1.8782x; 1.8782x over previous
//
#include <hip/hip_runtime.h>
#include <hip/hip_bf16.h>
#include <stdint.h>

typedef unsigned short ushort_t;
typedef unsigned int uint_t;

typedef __bf16 bf16x8 __attribute__((ext_vector_type(8)));
typedef float f32x4 __attribute__((ext_vector_type(4)));
typedef short short4v __attribute__((ext_vector_type(4)));
typedef short short8v __attribute__((ext_vector_type(8)));

typedef const __attribute__((address_space(1))) void gv_t;
typedef __attribute__((address_space(3))) void lv_t;

__device__ __forceinline__ ushort_t f2b(float f) {
  uint_t u = __builtin_bit_cast(uint_t, f);
  u += 0x7FFFu + ((u >> 16) & 1u);   // round-to-nearest-even
  return (ushort_t)(u >> 16);
}
__device__ __forceinline__ float b2f(ushort_t s) {
  return __builtin_bit_cast(float, (uint_t)s << 16);
}
constexpr int ilog2c(int x) { return x <= 1 ? 0 : 1 + ilog2c(x >> 1); }

constexpr int Tt = 16, Cc = 256, Hh = 64, Ww = 64, DKc = 128;
constexpr size_t P1OFFc = 16777216;   // patch-1 offset within token regions (elems)

// ---------------- tokenize Q and K, LDS-free register transpose (R11-verified) ----------------
__global__ __launch_bounds__(256) void tok_qk3(const float* __restrict__ srcQ, const float* __restrict__ srcK,
                                               ushort_t* __restrict__ dstQ, ushort_t* __restrict__ dstK) {
  const int blk = blockIdx.x;
  const int sel = blk >> 11;
  const int bt  = (blk >> 6) & 31;
  const int cg  = blk & 63;
  const int b = bt >> 4, t = bt & 15;
  const float* src = sel ? srcK : srcQ;
  ushort_t* dst = sel ? dstK : dstQ;
  const int tid = threadIdx.x;
  const int w = tid >> 6, l = tid & 63;
  if (cg < 32) {
    const int c = cg * 4 + w;
    const float* img = src + (((size_t)(bt * 256 + c)) << 12);
    const int oh = l >> 3, ow = l & 7;
    ushort_t* out = dst + (((size_t)(b * 1024 + t * 64 + l)) << 13) + c * 64;
    const float* base = img + (oh * 8) * 64 + ow * 8;
#pragma unroll
    for (int py = 0; py < 8; ++py) {
      float4 f0 = *(const float4*)(base + py * 64);
      float4 f1 = *(const float4*)(base + py * 64 + 4);
      short8v o;
      o[0] = (short)f2b(f0.x); o[1] = (short)f2b(f0.y); o[2] = (short)f2b(f0.z); o[3] = (short)f2b(f0.w);
      o[4] = (short)f2b(f1.x); o[5] = (short)f2b(f1.y); o[6] = (short)f2b(f1.z); o[7] = (short)f2b(f1.w);
      *(short8v*)(out + py * 8) = o;
    }
  } else {
    const int c = 128 + (cg - 32) * 4 + w;
    const float* img = src + (((size_t)(bt * 256 + c)) << 12);
    const int ow = l & 15, ohg = l >> 4;
#pragma unroll
    for (int i = 0; i < 4; ++i) {
      const int oh = ohg + 4 * i;
      const int n = t * 256 + oh * 16 + ow;
      ushort_t* out = dst + P1OFFc + (((size_t)(b * 4096 + n)) << 11) + (c - 128) * 16;
      const float* basep = img + (oh * 4) * 64 + ow * 4;
      float4 f0 = *(const float4*)(basep);
      float4 f1 = *(const float4*)(basep + 64);
      float4 f2 = *(const float4*)(basep + 128);
      float4 f3 = *(const float4*)(basep + 192);
      short8v o0, o1;
      o0[0] = (short)f2b(f0.x); o0[1] = (short)f2b(f0.y); o0[2] = (short)f2b(f0.z); o0[3] = (short)f2b(f0.w);
      o0[4] = (short)f2b(f1.x); o0[5] = (short)f2b(f1.y); o0[6] = (short)f2b(f1.z); o0[7] = (short)f2b(f1.w);
      o1[0] = (short)f2b(f2.x); o1[1] = (short)f2b(f2.y); o1[2] = (short)f2b(f2.z); o1[3] = (short)f2b(f2.w);
      o1[4] = (short)f2b(f3.x); o1[5] = (short)f2b(f3.y); o1[6] = (short)f2b(f3.z); o1[7] = (short)f2b(f3.w);
      *(short8v*)out = o0;
      *(short8v*)(out + 8) = o1;
    }
  }
}

// ---------------- tokenize V transposed via LDS tile, [64][65] pad (R12-verified) ----------------
__global__ __launch_bounds__(256) void tok_v4(const float* __restrict__ src, ushort_t* __restrict__ dst) {
  __shared__ float lds[64][65];
  const int blk = blockIdx.x;
  const int c  = blk & 255;
  const int bt = blk >> 8;
  const int b  = bt >> 4, t = bt & 15;
  const int tid = threadIdx.x;
  const float* img = src + ((size_t)blk << 12);
  {
    const int h = tid >> 2, w0 = (tid & 3) << 4;
    const float* s = img + h * 64 + w0;
    float4 f0 = *(const float4*)(s);
    float4 f1 = *(const float4*)(s + 4);
    float4 f2 = *(const float4*)(s + 8);
    float4 f3 = *(const float4*)(s + 12);
    float* d = &lds[h][w0];
    d[0] = f0.x; d[1] = f0.y; d[2]  = f0.z; d[3]  = f0.w;
    d[4] = f1.x; d[5] = f1.y; d[6]  = f1.z; d[7]  = f1.w;
    d[8] = f2.x; d[9] = f2.y; d[10] = f2.z; d[11] = f2.w;
    d[12] = f3.x; d[13] = f3.y; d[14] = f3.z; d[15] = f3.w;
  }
  __syncthreads();
  if (c < 128) {
    const int dd = tid >> 2, cc = tid & 3;
    const int py = dd >> 3, px = dd & 7;
    ushort_t* out = dst + (((size_t)(b * 8192 + c * 64 + dd)) << 10) + t * 64 + cc * 16;
    short8v o0, o1;
#pragma unroll
    for (int j = 0; j < 8; ++j) {
      const int n = cc * 16 + j;
      o0[j] = (short)f2b(lds[(n >> 3) * 8 + py][(n & 7) * 8 + px]);
    }
#pragma unroll
    for (int j = 8; j < 16; ++j) {
      const int n = cc * 16 + j;
      o1[j - 8] = (short)f2b(lds[(n >> 3) * 8 + py][(n & 7) * 8 + px]);
    }
    *(short8v*)out = o0;
    *(short8v*)(out + 8) = o1;
  } else {
    const int dd = tid >> 4, cc = tid & 15;
    const int py = dd >> 2, px = dd & 3;
    ushort_t* out = dst + P1OFFc + (((size_t)(b * 2048 + (c - 128) * 16 + dd)) << 12) + t * 256 + cc * 16;
    short8v o0, o1;
#pragma unroll
    for (int j = 0; j < 8; ++j)
      o0[j] = (short)f2b(lds[cc * 4 + py][j * 4 + px]);
#pragma unroll
    for (int j = 8; j < 16; ++j)
      o1[j - 8] = (short)f2b(lds[cc * 4 + py][j * 4 + px]);
    *(short8v*)out = o0;
    *(short8v*)(out + 8) = o1;
  }
}

__device__ __forceinline__ void waitvm8() { asm volatile("s_waitcnt vmcnt(8)" ::: "memory"); }
__device__ __forceinline__ void waitvm6() { asm volatile("s_waitcnt vmcnt(6)" ::: "memory"); }
__device__ __forceinline__ void waitvm0() { asm volatile("s_waitcnt vmcnt(0)" ::: "memory"); }

// ---- 256x256/BK=64 double-buffered NT GEMM, 4 quadrant-phases/K-tile (R13-verified) ----
// 2 barriers per K-tile (end-P0, end-P2 after counted vmcnt(6)); read-ahead frags one
// phase early; persistent staging pointers advanced once per unrolled K-tile pair.
template<int EPI, int KSPLIT, int LDK, int NP, int PH, int PW, int CBASE>
__global__ __launch_bounds__(512, 2)
void gemm_pipe(const ushort_t* __restrict__ A, const ushort_t* __restrict__ B,
               size_t aBatch, size_t bBatch, int nt,
               void* __restrict__ outPtr, size_t oBatch, float scale) {
  __shared__ __align__(16) ushort_t As[2 * 256 * 64];
  __shared__ __align__(16) ushort_t Bs[2 * 256 * 64];

  const int tid = threadIdx.x;
  const int w = tid >> 6, l = tid & 63;
  const int wm = w >> 2, wn = w & 3;
  const int lr = l & 15, lk = l >> 4;
  const int srow8 = tid >> 3;
  const int gcolS = (((tid & 7) ^ (srow8 & 7)) << 3);
  const int sw0 = ((lk ^ (lr & 7)) << 4);
  const int sw1 = sw0 ^ 64;

  const int gx = gridDim.x, gy = gridDim.y, gz = gridDim.z;
  int id = (blockIdx.z * gy + blockIdx.y) * gx + blockIdx.x;
  const int cpx = (gx * gy * gz) >> 3;
  id = (id & 7) * cpx + (id >> 3);
  const int bx = id % gx;
  const int rst = id / gx;
  const int by = rst % gy;
  const int bz = rst / gy;

  int batch = bz, ks = 0;
  if constexpr (KSPLIT > 1) { batch = bz / KSPLIT; ks = bz - batch * KSPLIT; }

  const int rowBase = by * 256, colBase = bx * 256;
  const ushort_t* Ab = A + (size_t)batch * aBatch + (size_t)ks * nt * 64;
  const ushort_t* Bb = B + (size_t)batch * bBatch + (size_t)ks * nt * 64;

  const ushort_t* pA[4];
  const ushort_t* pB[4];
#pragma unroll
  for (int r = 0; r < 4; ++r) {
    pA[r] = Ab + (size_t)(rowBase + r * 64 + srow8) * LDK + gcolS;
    pB[r] = Bb + (size_t)(colBase + r * 64 + srow8) * LDK + gcolS;
  }

  const char* ArdBase0 = (const char*)As + (wm * 128 + lr) * 128 + sw0;
  const char* ArdBase1 = (const char*)As + (wm * 128 + lr) * 128 + sw1;
  const char* BrdBase0 = (const char*)Bs + (wn * 64 + lr) * 128 + sw0;
  const char* BrdBase1 = (const char*)Bs + (wn * 64 + lr) * 128 + sw1;

  f32x4 acc[8][4] = {};
  bf16x8 Am0[8], Am1[8], Bn0[4], Bn1[4];

  auto stgA = [&](int bufB, int r, int elemOff) {
    __builtin_amdgcn_global_load_lds((gv_t*)(pA[r] + elemOff),
        (lv_t*)((char*)As + bufB + r * 8192 + w * 1024), 16, 0, 0);
  };
  auto stgB = [&](int bufB, int r, int elemOff) {
    __builtin_amdgcn_global_load_lds((gv_t*)(pB[r] + elemOff),
        (lv_t*)((char*)Bs + bufB + r * 8192 + w * 1024), 16, 0, 0);
  };
  auto rdA = [&](int off, bf16x8* dst) {
#pragma unroll
    for (int mi = 0; mi < 4; ++mi) {
      dst[mi * 2 + 0] = *(const bf16x8*)(ArdBase0 + off + mi * 2048);
      dst[mi * 2 + 1] = *(const bf16x8*)(ArdBase1 + off + mi * 2048);
    }
  };
  auto rdB = [&](int off, bf16x8* dst) {
#pragma unroll
    for (int ni = 0; ni < 2; ++ni) {
      dst[ni * 2 + 0] = *(const bf16x8*)(BrdBase0 + off + ni * 2048);
      dst[ni * 2 + 1] = *(const bf16x8*)(BrdBase1 + off + ni * 2048);
    }
  };
  auto mmq = [&](const bf16x8* a, const bf16x8* b, int mh, int nh) {
    __builtin_amdgcn_s_setprio(1);
#pragma unroll
    for (int mi = 0; mi < 4; ++mi)
#pragma unroll
      for (int ni = 0; ni < 2; ++ni) {
        f32x4& cc = acc[mh * 4 + mi][nh * 2 + ni];
        cc = __builtin_amdgcn_mfma_f32_16x16x32_bf16(a[mi * 2 + 0], b[ni * 2 + 0], cc, 0, 0, 0);
        cc = __builtin_amdgcn_mfma_f32_16x16x32_bf16(a[mi * 2 + 1], b[ni * 2 + 1], cc, 0, 0, 0);
      }
    __builtin_amdgcn_s_setprio(0);
  };

#pragma unroll
  for (int r = 0; r < 4; ++r) stgA(0, r, 0);
#pragma unroll
  for (int r = 0; r < 4; ++r) stgB(0, r, 0);
#pragma unroll
  for (int r = 0; r < 4; ++r) stgA(32768, r, 64);
#pragma unroll
  for (int r = 0; r < 4; ++r) stgB(32768, r, 64);
#pragma unroll
  for (int r = 0; r < 4; ++r) { pA[r] += 128; pB[r] += 128; }
  waitvm8();
  __builtin_amdgcn_s_barrier();
  rdA(0, Am0);
  rdB(0, Bn0);

// 2 barriers per K-tile: end-P0 and end-P2 (after counted vmcnt).
#define TB(T, BUFB, EOFF, ADV) do {                                             \
    const int OB = (BUFB) ^ 32768;                                              \
    /* P0: MFMA q(0,0); read-ahead B-half1 */                                   \
    rdB((BUFB) + 4096, Bn1);                                                    \
    mmq(Am0, Bn0, 0, 0);                                                        \
    __builtin_amdgcn_s_barrier();                                               \
    /* P1: MFMA q(0,1); read-ahead A-half1; stage t+2 A rounds 0,2 */           \
    rdA((BUFB) + 8192, Am1);                                                    \
    if ((T) + 2 < nt) { stgA((BUFB), 0, (EOFF)); stgA((BUFB), 2, (EOFF)); }     \
    mmq(Am0, Bn1, 0, 1);                                                        \
    /* P2: MFMA q(1,0); stage t+2 B all; counted drain before kept barrier */   \
    if ((T) + 2 < nt) { stgB((BUFB), 0, (EOFF)); stgB((BUFB), 1, (EOFF));       \
                        stgB((BUFB), 2, (EOFF)); stgB((BUFB), 3, (EOFF)); }     \
    mmq(Am1, Bn0, 1, 0);                                                        \
    if ((T) + 2 < nt) waitvm6(); else if ((T) + 1 < nt) waitvm0();              \
    __builtin_amdgcn_s_barrier();                                               \
    /* P3: MFMA q(1,1); read-ahead next tile A0,B0; stage t+2 A rounds 1,3 */   \
    if ((T) + 1 < nt) { rdA(OB, Am0); rdB(OB, Bn0); }                           \
    if ((T) + 2 < nt) {                                                         \
      stgA((BUFB), 1, (EOFF)); stgA((BUFB), 3, (EOFF));                         \
      if (ADV) {                                                                \
        _Pragma("unroll")                                                       \
        for (int r = 0; r < 4; ++r) { pA[r] += 128; pB[r] += 128; }             \
      }                                                                         \
    }                                                                           \
    mmq(Am1, Bn1, 1, 1);                                                        \
  } while (0)

  for (int t = 0; t < nt; t += 2) {
    TB(t, 0, 0, 0);
    TB(t + 1, 32768, 64, 1);
  }
#undef TB

  if constexpr (EPI == 0) {
    ushort_t* P = (ushort_t*)outPtr + (size_t)batch * oBatch;
#pragma unroll
    for (int mi = 0; mi < 8; ++mi) {
      const int row0 = rowBase + wm * 128 + mi * 16 + lk * 4;
#pragma unroll
      for (int ni = 0; ni < 4; ++ni) {
        const int col = colBase + wn * 64 + ni * 16 + lr;
#pragma unroll
        for (int r = 0; r < 4; ++r)
          P[(size_t)(row0 + r) * NP + col] = f2b(acc[mi][ni][r] * scale);
      }
    }
  } else if constexpr (EPI == 1) {
    float* O = (float*)outPtr;
    constexpr int OWN = Ww / PW;
    constexpr int OHW = (Hh / PH) * OWN;
    constexpr int PHPW = PH * PW;
#pragma unroll
    for (int mi = 0; mi < 8; ++mi) {
#pragma unroll
      for (int ni = 0; ni < 4; ++ni) {
        const int d = colBase + wn * 64 + ni * 16 + lr;
        const int c   = d >> ilog2c(PHPW);
        const int pyx = d & (PHPW - 1);
        const int py  = pyx >> ilog2c(PW);
        const int px  = pyx & (PW - 1);
#pragma unroll
        for (int r = 0; r < 4; ++r) {
          const int qq = rowBase + wm * 128 + mi * 16 + lk * 4 + r;
          const int tt = qq >> ilog2c(OHW);
          const int rm = qq & (OHW - 1);
          const int oh = rm >> ilog2c(OWN);
          const int ow = rm & (OWN - 1);
          size_t off = (((size_t)((batch * Tt + tt) * Cc + CBASE + c)) << 12)
                     + ((oh * PH + py) << 6) + ow * PW + px;
          O[off] = acc[mi][ni][r];
        }
      }
    }
  } else {
    const int nb = gz / KSPLIT;
    ushort_t* O = (ushort_t*)outPtr + ((size_t)ks * nb + batch) * oBatch;
#pragma unroll
    for (int mi = 0; mi < 8; ++mi) {
      const int row0 = rowBase + wm * 128 + mi * 16 + lk * 4;
#pragma unroll
      for (int ni = 0; ni < 4; ++ni) {
        const int col = colBase + wn * 64 + ni * 16 + lr;
#pragma unroll
        for (int r = 0; r < 4; ++r)
          O[(size_t)(row0 + r) * NP + col] = f2b(acc[mi][ni][r] * scale);
      }
    }
  }
}

// ---------------- row softmax over bf16 scores, in place ----------------
template<int NP>
__global__ __launch_bounds__(256) void softmax_rows(ushort_t* __restrict__ P) {
  constexpr int PER = NP / 256;
  constexpr int CH  = NP / 1024;
  ushort_t* row = P + (size_t)blockIdx.x * NP;
  const int tid = threadIdx.x;
  float v[PER];
  #pragma unroll
  for (int j = 0; j < CH; ++j) {
    short4v s = *(const short4v*)(row + j * 1024 + tid * 4);
    #pragma unroll
    for (int jj = 0; jj < 4; ++jj) v[4 * j + jj] = b2f((ushort_t)s[jj]);
  }
  float m = -1e30f;
  #pragma unroll
  for (int j = 0; j < PER; ++j) m = fmaxf(m, v[j]);
  #pragma unroll
  for (int o = 32; o >= 1; o >>= 1) m = fmaxf(m, __shfl_xor(m, o));
  __shared__ float redm[4];
  if ((tid & 63) == 0) redm[tid >> 6] = m;
  __syncthreads();
  m = fmaxf(fmaxf(redm[0], redm[1]), fmaxf(redm[2], redm[3]));
  float sum = 0.f;
  #pragma unroll
  for (int j = 0; j < PER; ++j) { v[j] = __expf(v[j] - m); sum += v[j]; }
  #pragma unroll
  for (int o = 32; o >= 1; o >>= 1) sum += __shfl_xor(sum, o);
  __shared__ float reds[4];
  if ((tid & 63) == 0) reds[tid >> 6] = sum;
  __syncthreads();
  sum = reds[0] + reds[1] + reds[2] + reds[3];
  const float inv = 1.0f / sum;
  #pragma unroll
  for (int j = 0; j < CH; ++j) {
    short4v o;
    #pragma unroll
    for (int jj = 0; jj < 4; ++jj) o[jj] = (short)f2b(v[4 * j + jj] * inv);
    *(short4v*)(row + j * 1024 + tid * 4) = o;
  }
}

// ---------------- combine 8 bf16 split-K partials + softmax -> bf16 P (patch 0) ----------------
__global__ __launch_bounds__(256) void softmax_combine_p0(const ushort_t* __restrict__ part,
                                                          ushort_t* __restrict__ P) {
  const int tid = threadIdx.x;
  const int b = blockIdx.x >> 10;
  const int m = blockIdx.x & 1023;
  float v[4] = {0.f, 0.f, 0.f, 0.f};
  #pragma unroll
  for (int ks = 0; ks < 8; ++ks) {
    short4v a = *(const short4v*)(part + ((size_t)(ks * 2 + b) * 1024 + m) * 1024 + tid * 4);
    #pragma unroll
    for (int j = 0; j < 4; ++j) v[j] += b2f((ushort_t)a[j]);
  }
  float mx = fmaxf(fmaxf(v[0], v[1]), fmaxf(v[2], v[3]));
  #pragma unroll
  for (int o = 32; o >= 1; o >>= 1) mx = fmaxf(mx, __shfl_xor(mx, o));
  __shared__ float redm[4], reds[4];
  if ((tid & 63) == 0) redm[tid >> 6] = mx;
  __syncthreads();
  mx = fmaxf(fmaxf(redm[0], redm[1]), fmaxf(redm[2], redm[3]));
  float sum = 0.f;
  #pragma unroll
  for (int j = 0; j < 4; ++j) { v[j] = __expf(v[j] - mx); sum += v[j]; }
  #pragma unroll
  for (int o = 32; o >= 1; o >>= 1) sum += __shfl_xor(sum, o);
  if ((tid & 63) == 0) reds[tid >> 6] = sum;
  __syncthreads();
  sum = reds[0] + reds[1] + reds[2] + reds[3];
  const float inv = 1.0f / sum;
  short4v o4;
  #pragma unroll
  for (int j = 0; j < 4; ++j) o4[j] = (short)f2b(v[j] * inv);
  *(short4v*)(P + ((size_t)(b * 1024 + m)) * 1024 + tid * 4) = o4;
}

extern "C" void kernel_launch(void* const* d_in, const int* in_sizes, int n_in,
                              void* d_out, int out_size, void* d_ws, size_t ws_size,
                              hipStream_t stream) {
  const float* q = (const float*)d_in[0];
  const float* k = (const float*)d_in[1];
  const float* v = (const float*)d_in[2];
  ushort_t* wsA = (ushort_t*)d_ws;
  ushort_t* wsB = wsA + (size_t)33554432;          // 64 MiB in
  ushort_t* wsP = wsB + (size_t)33554432;          // 128 MiB in
  const size_t P1OFF = P1OFFc;                     // patch-1 offset within A/B regions (elems)
  const size_t PP1   = 2097152;                    // patch-1 offset within P region (elems)
  ushort_t* part = wsP + PP1;                      // QK-p0 bf16 split-K partials (32 MiB), overlaid on P-p1

  // tokenize Q and K (merged, both patches, LDS-free register transpose)
  tok_qk3<<<4096, 256, 0, stream>>>(q, k, wsA, wsB);

  // QK p0: split-K=8 -> bf16 partials [ks][b][1024][1024]; fused combine+softmax
  gemm_pipe<2, 8, 8192, 1024, 1, 1, 0><<<dim3(4, 4, 16), 512, 0, stream>>>(
      wsA, wsB, (size_t)1024 * 8192, (size_t)1024 * 8192, 16,
      part, (size_t)1048576, 0.011048543456039806f);
  softmax_combine_p0<<<2048, 256, 0, stream>>>(part, wsP);

  // QK p1 (overwrites partial region AFTER combine consumed it)
  gemm_pipe<0, 1, 2048, 4096, 1, 1, 0><<<dim3(16, 16, 2), 512, 0, stream>>>(
      wsA + P1OFF, wsB + P1OFF, (size_t)4096 * 2048, (size_t)4096 * 2048, 32,
      wsP + PP1, (size_t)4096 * 4096, 0.022097086912079612f);
  softmax_rows<4096><<<8192, 256, 0, stream>>>(wsP + PP1);

  // tokenize V transposed into A region (Q tokens no longer needed)
  tok_v4<<<8192, 256, 0, stream>>>(v, wsA);

  // O = P * V -> scatter fp32 into d_out
  gemm_pipe<1, 1, 1024, 0, 8, 8, 0><<<dim3(32, 4, 2), 512, 0, stream>>>(
      wsP, wsA, (size_t)1024 * 1024, (size_t)8192 * 1024, 16, d_out, 0, 1.0f);
  gemm_pipe<1, 1, 4096, 0, 4, 4, 128><<<dim3(8, 16, 2), 512, 0, stream>>>(
      wsP + PP1, wsA + P1OFF, (size_t)4096 * 4096, (size_t)2048 * 4096, 64, d_out, 0, 1.0f);
}